// Round 14
// baseline (227.110 us; speedup 1.0000x reference)
//
#include <hip/hip_runtime.h>

// GCN forward. All inter-kernel feature traffic in bf16.
//   xb  = bf16(x * dinv_row)                       (fused into scatter)
//   axb = bf16(dd*(Σ_{s} xb[s] + xb[d]))           (agg1, bf16 out)
//   fused MLP: a1 = relu(axb@W1+b1) [LDS only] ; h2b = bf16((a1@W2)*dinv)
//   agg2+pool: pool[g] += relu(dd*(Σ h2b[s] + h2b[d]) + b2)   (fused, no a2b)
//   out = pool/cnt @ Wfc + bfc
// R29: amortize the (confirmed) streaming weight traffic. R28 proved the MLP
// was bound by the weight-fetch PATTERN (contiguous slabs: 48.2 -> ~27us,
// total 240 -> 225.7). Remaining mlp cost ~ 256KB/block x 1042 blocks = 267MB
// L2 streaming. This round: M-tile 48 -> 96 rows (6 m-frags), grid 521 ->
// weight traffic halves to 133MB. NO register residency across loops (R27's
// spill trap): weights stay in-loop 32-VGPR batches; peak live ~165 VGPR.
// LDS 72KB (A1 48KB + A0 24KB) -> 2 blocks/CU (occupancy-insensitive kernel,
// proven R21-R23). MFMA order per output unchanged -> bit-identical numerics.
// Tell: WRITE_SIZE stays ~12.5MB (no spill); mlp -> 16-20us.
// R28 (kept): fragment-ordered weight slabs. R20/R17 (kept). 9 dispatches.

constexpr int IN_DIM  = 128;
constexpr int HID     = 256;
constexpr int HID2    = 128;
constexpr int OUT_DIM = 4;
constexpr int NGRAPH  = 64;

typedef __attribute__((ext_vector_type(8))) short bf16x8;
typedef __attribute__((ext_vector_type(4))) float f32x4;

__device__ __forceinline__ short f2bf(float f) {
    union { float f; unsigned u; } v; v.f = f;
    unsigned r = v.u + 0x7fff + ((v.u >> 16) & 1);   // RNE
    return (short)(r >> 16);
}
__device__ __forceinline__ float bf2f(short s) {
    union { unsigned u; float f; } v; v.u = ((unsigned)(unsigned short)s) << 16;
    return v.f;
}

// ------- W prep: FRAGMENT-ORDER planes + count zero + pool zero -------
// W1 plane: 64 slabs of 512 shorts; slab = c4*4 + ks (c4 = col/16, ks = k/32).
//   element i: lane=(i>>3)&63, e=i&7 -> value W1[k][col],
//   col = c4*16 + (lane&15), k = ks*32 + (lane>>4)*8 + e.
// W2 plane: 64 slabs; slab = c4*8 + ks (c4 = col/16, ks = k/32, ks<8).
// A wave's fragment load is then 64 lanes x 16B CONTIGUOUS (1KB streaming).

__global__ void wprep_all_kernel(const float* __restrict__ W1, short* __restrict__ W1fh,
                                 short* __restrict__ W1fl,
                                 const float* __restrict__ W2, short* __restrict__ W2fh,
                                 short* __restrict__ W2fl,
                                 int* __restrict__ count, float* __restrict__ pool, int N) {
    int i = blockIdx.x * blockDim.x + threadIdx.x;
    if (i < IN_DIM * HID) {                    // 32768 = W1 plane
        int slab = i >> 9, lane = (i >> 3) & 63, e = i & 7;
        int c4 = slab >> 2, ks = slab & 3;
        int col = c4 * 16 + (lane & 15);
        int k   = ks * 32 + (lane >> 4) * 8 + e;
        float w = W1[k * HID + col];
        short h = f2bf(w);
        W1fh[i] = h;
        W1fl[i] = f2bf(w - bf2f(h));
    }
    if (i < HID * HID2) {                      // 32768 = W2 plane
        int slab = i >> 9, lane = (i >> 3) & 63, e = i & 7;
        int c4 = slab >> 3, ks = slab & 7;
        int col = c4 * 16 + (lane & 15);
        int k   = ks * 32 + (lane >> 4) * 8 + e;
        float w = W2[k * HID2 + col];
        short h = f2bf(w);
        W2fh[i] = h;
        W2fl[i] = f2bf(w - bf2f(h));
    }
    if (i < N) count[i] = 0;
    if (i < NGRAPH * HID2) pool[i] = 0.f;
}

// ---------------- CSR build ----------------

__global__ void hist_kernel(const int* __restrict__ dst, int* __restrict__ count,
                            ushort* __restrict__ rank, int E) {
    int i = blockIdx.x * blockDim.x + threadIdx.x;
    if (i < E) rank[i] = (ushort)atomicAdd(&count[dst[i]], 1);
}

__global__ void scan1_kernel(const int* __restrict__ count, int* __restrict__ bsums, int N) {
    __shared__ int s[256];
    int t = threadIdx.x, i = blockIdx.x * 256 + t;
    int v = (i < N) ? count[i] : 0;
    s[t] = v; __syncthreads();
    for (int o = 1; o < 256; o <<= 1) {
        int x = (t >= o) ? s[t - o] : 0;
        __syncthreads(); s[t] += x; __syncthreads();
    }
    if (t == 255) bsums[blockIdx.x] = s[255];
}

// scan3: inline-scan the (<=256) raw block sums, then per-element scan of count.
__global__ void scan3_kernel(const int* __restrict__ count, const int* __restrict__ bsums,
                             int* __restrict__ rowptr, float* __restrict__ dinv,
                             int N, int E, int nb) {
    __shared__ int sb[256];
    __shared__ int s[256];
    int t = threadIdx.x, i = blockIdx.x * 256 + t;
    int bv = (t < nb) ? bsums[t] : 0;
    sb[t] = bv; __syncthreads();
    for (int o = 1; o < 256; o <<= 1) {
        int x = (t >= o) ? sb[t - o] : 0;
        __syncthreads(); sb[t] += x; __syncthreads();
    }
    int myex = (blockIdx.x == 0) ? 0 : sb[blockIdx.x - 1];
    int v = (i < N) ? count[i] : 0;
    s[t] = v; __syncthreads();
    for (int o = 1; o < 256; o <<= 1) {
        int x = (t >= o) ? s[t - o] : 0;
        __syncthreads(); s[t] += x; __syncthreads();
    }
    if (i < N) {
        rowptr[i] = myex + s[t] - v;
        dinv[i] = rsqrtf((float)v + 1.0f);
        if (i == 0) rowptr[N] = E;
    }
}

// scatter (no atomics: p = rowptr[dst]+rank) + xb = bf16(x * dinv_row)
__global__ void scatter_scale_kernel(const int* __restrict__ src, const int* __restrict__ dst,
                                     const ushort* __restrict__ rank,
                                     const int* __restrict__ rowptr, ushort* __restrict__ csr,
                                     const float* __restrict__ x, const float* __restrict__ dinv,
                                     ushort* __restrict__ xb, int E, int total2) {
    int i = blockIdx.x * blockDim.x + threadIdx.x;
    if (i < E) {
        int p = rowptr[dst[i]] + (int)rank[i];
        csr[p] = (ushort)src[i];
    }
    if (i < total2) {
        float d = dinv[i >> 6];
        float2 v = ((const float2*)x)[i];
        ushort2 o;
        o.x = (ushort)f2bf(v.x * d);
        o.y = (ushort)f2bf(v.y * d);
        ((ushort2*)xb)[i] = o;
    }
}

// ---------------- fused MLP: h2b = bf16((relu(axb@W1+b1)@W2)*dinv) ----------------
// One block per 96-row M-tile (grid 521), 256 thr = 4 waves. Weights fragment-
// ordered: one wave-load = contiguous 1KB slab (R28-confirmed). In-loop loads
// only (no cross-loop residency -> no spill). Wave w: phase1 cols w*64..
// (6m x 4n frags), phase2 cols w*32 (6m x 2n).
//   W1 slab = ((w*4+n)*4+ks)*512;  W2 slab = ((w*2+n)*8+ks)*512; + lane*8.
// A0 (24 KB, 24 slabs): axb in frag layout; slab s: m=s>>2, ks=s&3.
// A1 (48 KB, 48 slabs): a1 in frag layout, identity:
//   element (r,c) -> slab (r>>4)*8+(c>>5), lane d=(r&15)+16*((c>>3)&3), e=c&7
// OUT (96x132) overlays A1 after phase2. 4 barriers. Bit-identical numerics.

__launch_bounds__(256, 2)
__global__ void mlp_fused_kernel(const short* __restrict__ A,
                                 const short* __restrict__ W1h, const short* __restrict__ W1l,
                                 const float* __restrict__ b1,
                                 const short* __restrict__ W2h, const short* __restrict__ W2l,
                                 const float* __restrict__ dinv,
                                 short* __restrict__ Cb, int M) {
    __shared__ __align__(16) short L[24576 + 12288];  // A1 (48 slabs) | A0 (24 slabs)
    short* A1 = L;
    short* A0 = L + 24576;
    __shared__ float dinv_s[96];

    const int tid  = threadIdx.x;
    const int w    = tid >> 6;
    const int lane = tid & 63;
    const int l15  = lane & 15;
    const int kq8  = (lane >> 4) * 8;
    const int row0 = blockIdx.x * 96;

    // ---- stage A0 (24 slabs; wave w -> slabs 6w..6w+5) ----
    {
        bf16x8 stg[6];
#pragma unroll
        for (int j = 0; j < 6; ++j) {
            int s = w * 6 + j;
            int m = s >> 2, ks = s & 3;
            int rr = row0 + m * 16 + l15; if (rr >= M) rr = M - 1;
            stg[j] = *(const bf16x8*)(A + (size_t)rr * IN_DIM + ks * 32 + kq8);
        }
#pragma unroll
        for (int j = 0; j < 6; ++j)
            *(bf16x8*)&A0[(w * 6 + j) * 512 + lane * 8] = stg[j];
    }
    if (tid < 96) { int r = row0 + tid; dinv_s[tid] = dinv[r < M ? r : M - 1]; }
    __syncthreads();

    // ---- phase 1: a1 = axb @ W1^T (split B), K=128; contiguous slab loads ----
    f32x4 acc1[6][4];
#pragma unroll
    for (int m = 0; m < 6; ++m)
#pragma unroll
        for (int n = 0; n < 4; ++n) acc1[m][n] = f32x4{0.f, 0.f, 0.f, 0.f};

#pragma unroll
    for (int ks = 0; ks < 4; ++ks) {
        bf16x8 af[6], bh[4], bl[4];
#pragma unroll
        for (int m = 0; m < 6; ++m) af[m] = *(const bf16x8*)&A0[(m * 4 + ks) * 512 + lane * 8];
#pragma unroll
        for (int n = 0; n < 4; ++n) {
            int slab = ((w * 4 + n) * 4 + ks) * 512;
            bh[n] = *(const bf16x8*)(W1h + slab + lane * 8);
            bl[n] = *(const bf16x8*)(W1l + slab + lane * 8);
        }
#pragma unroll
        for (int m = 0; m < 6; ++m)
#pragma unroll
            for (int n = 0; n < 4; ++n) {
                acc1[m][n] = __builtin_amdgcn_mfma_f32_16x16x32_bf16(af[m], bh[n], acc1[m][n], 0, 0, 0);
                acc1[m][n] = __builtin_amdgcn_mfma_f32_16x16x32_bf16(af[m], bl[n], acc1[m][n], 0, 0, 0);
            }
    }

    // ---- bias + relu + bf16, transpose-write into A1 (identity mapping) ----
#pragma unroll
    for (int n = 0; n < 4; ++n) {
        int c  = w * 64 + n * 16 + l15;
        float bv = b1[c];
        int kst = c >> 5;
        int q  = (c >> 3) & 3;
        int e  = c & 7;
#pragma unroll
        for (int m = 0; m < 6; ++m)
#pragma unroll
            for (int r4 = 0; r4 < 4; ++r4) {
                int rl = (lane >> 4) * 4 + r4;                 // r & 15
                int d  = rl + 16 * q;                          // dest lane 0..63
                float v = fmaxf(acc1[m][n][r4] + bv, 0.f);
                A1[(m * 8 + kst) * 512 + d * 8 + e] = f2bf(v);
            }
    }
    __syncthreads();

    // ---- phase 2: h2 = a1 @ W2^T (split B), K=256; contiguous slab loads ----
    f32x4 acc2[6][2];
#pragma unroll
    for (int m = 0; m < 6; ++m)
#pragma unroll
        for (int n = 0; n < 2; ++n) acc2[m][n] = f32x4{0.f, 0.f, 0.f, 0.f};

#pragma unroll
    for (int ks = 0; ks < 8; ++ks) {
        bf16x8 af[6], bh[2], bl[2];
#pragma unroll
        for (int m = 0; m < 6; ++m) af[m] = *(const bf16x8*)&A1[(m * 8 + ks) * 512 + lane * 8];
#pragma unroll
        for (int n = 0; n < 2; ++n) {
            int slab = ((w * 2 + n) * 8 + ks) * 512;
            bh[n] = *(const bf16x8*)(W2h + slab + lane * 8);
            bl[n] = *(const bf16x8*)(W2l + slab + lane * 8);
        }
#pragma unroll
        for (int m = 0; m < 6; ++m)
#pragma unroll
            for (int n = 0; n < 2; ++n) {
                acc2[m][n] = __builtin_amdgcn_mfma_f32_16x16x32_bf16(af[m], bh[n], acc2[m][n], 0, 0, 0);
                acc2[m][n] = __builtin_amdgcn_mfma_f32_16x16x32_bf16(af[m], bl[n], acc2[m][n], 0, 0, 0);
            }
    }
    __syncthreads();          // A1 reads done before OUT overlays it

    // ---- epilogue: dinv scale -> OUT tile (overlays A1) -> coalesced store ----
    short* T = A1;                                    // 96 x 132 shorts (12672 < 24576)
#pragma unroll
    for (int n = 0; n < 2; ++n) {
        int c = w * 32 + n * 16 + l15;
#pragma unroll
        for (int m = 0; m < 6; ++m)
#pragma unroll
            for (int r4 = 0; r4 < 4; ++r4) {
                int r = m * 16 + (lane >> 4) * 4 + r4;
                T[r * 132 + c] = f2bf(acc2[m][n][r4] * dinv_s[r]);
            }
    }
    __syncthreads();
#pragma unroll
    for (int it = 0; it < 6; ++it) {
        int chunk = it * 256 + tid;                   // 1536 chunks of 8 shorts
        int lr = chunk >> 4;
        int lc = (chunk & 15) * 8;
        int gr = row0 + lr;
        if (gr < M)
            *(bf16x8*)(Cb + (size_t)gr * HID2 + lc) = *(const bf16x8*)&T[lr * 132 + lc];
    }
}

// ---------------- group-per-node bf16 gather aggregation (D=128) ----------------
// One 16-lane group per dst node: 4 nodes/wave, 16 nodes/block (256 thr).
// 16 clamped 16B gathers issued per 16-edge chunk before accumulation
// -> 32-64 independent loads in flight per wave. 256B contiguous writes.
// POOL: bias+relu then 16-node LDS block-reduce by graph run -> atomicAdd.

template <bool POOL>
__launch_bounds__(256)
__global__ void agg_group_kernel(const ushort* __restrict__ hb, const float* __restrict__ dinv,
                                 const int* __restrict__ rowptr, const ushort* __restrict__ csr,
                                 const float* __restrict__ bias,
                                 short* __restrict__ oh,
                                 const int* __restrict__ batch, float* __restrict__ pool,
                                 int N) {
    __shared__ float pacc[16][128];
    __shared__ int   sgid[16];

    const int tid  = threadIdx.x;
    const int li   = tid & 15;
    const int nib  = tid >> 4;
    const int node = blockIdx.x * 16 + nib;
    const bool valid = node < N;
    if (!POOL && !valid) return;
    const int cw = valid ? node : N - 1;

    const int lo = rowptr[cw], hi = rowptr[cw + 1];
    const float dd = dinv[cw];

    float a[8];
    {
        bf16x8 sv = *(const bf16x8*)(hb + ((size_t)cw << 7) + (li << 3));
#pragma unroll
        for (int d = 0; d < 8; ++d) a[d] = bf2f(sv[d]);
    }

    const ushort* hsl = hb + (li << 3);

    for (int base = lo; base < hi; base += 16) {
        int cnt = min(16, hi - base);
        int sidx = (int)csr[base + (li < cnt ? li : cnt - 1)];
        bf16x8 p[8], q[8];
#pragma unroll
        for (int u = 0; u < 8; ++u) {
            int s = __shfl(sidx, u < cnt ? u : cnt - 1, 16);
            p[u] = *(const bf16x8*)(hsl + ((size_t)s << 7));
        }
#pragma unroll
        for (int u = 0; u < 8; ++u) {
            int e = 8 + u;
            int s = __shfl(sidx, e < cnt ? e : cnt - 1, 16);
            q[u] = *(const bf16x8*)(hsl + ((size_t)s << 7));
        }
#pragma unroll
        for (int u = 0; u < 8; ++u) {
            bool v = u < cnt;
#pragma unroll
            for (int d = 0; d < 8; ++d) a[d] += v ? bf2f(p[u][d]) : 0.f;
        }
#pragma unroll
        for (int u = 0; u < 8; ++u) {
            bool v = 8 + u < cnt;
#pragma unroll
            for (int d = 0; d < 8; ++d) a[d] += v ? bf2f(q[u][d]) : 0.f;
        }
    }

#pragma unroll
    for (int d = 0; d < 8; ++d) a[d] *= dd;

    if (!POOL) {
        if (valid) {
            bf16x8 o;
#pragma unroll
            for (int d = 0; d < 8; ++d) o[d] = f2bf(a[d]);
            *(bf16x8*)&oh[(size_t)node * 128 + li * 8] = o;
        }
        return;
    }

    {
        float4 b0 = ((const float4*)bias)[li * 2];
        float4 b1 = ((const float4*)bias)[li * 2 + 1];
        a[0] = fmaxf(a[0] + b0.x, 0.f); a[1] = fmaxf(a[1] + b0.y, 0.f);
        a[2] = fmaxf(a[2] + b0.z, 0.f); a[3] = fmaxf(a[3] + b0.w, 0.f);
        a[4] = fmaxf(a[4] + b1.x, 0.f); a[5] = fmaxf(a[5] + b1.y, 0.f);
        a[6] = fmaxf(a[6] + b1.z, 0.f); a[7] = fmaxf(a[7] + b1.w, 0.f);
    }
    if (li == 0) sgid[nib] = valid ? batch[node] : -1;
#pragma unroll
    for (int d = 0; d < 8; ++d) pacc[nib][li * 8 + d] = a[d];
    __syncthreads();
    if (tid < 128) {
        int c = tid;
        int cur = sgid[0];
        float run = 0.f;
#pragma unroll 1
        for (int w = 0; w < 16; ++w) {
            int gi = sgid[w];
            if (gi < 0) break;
            if (gi != cur) { atomicAdd(&pool[cur * HID2 + c], run); run = 0.f; cur = gi; }
            run += pacc[w][c];
        }
        atomicAdd(&pool[cur * HID2 + c], run);
    }
}

// ---------------- fc ----------------

__device__ __forceinline__ int lower_bound_i(const int* __restrict__ a, int n, int key) {
    int lo = 0, hi = n;
    while (lo < hi) {
        int mid = (lo + hi) >> 1;
        if (a[mid] < key) lo = mid + 1; else hi = mid;
    }
    return lo;
}

__global__ void fc_kernel(const float* __restrict__ pool, const int* __restrict__ batch,
                          const float* __restrict__ Wfc, const float* __restrict__ bfc,
                          float* __restrict__ out, int N) {
    int t = threadIdx.x;  // 256 = 64 graphs * 4 outputs
    int g = t >> 2, o = t & 3;
    int lo = lower_bound_i(batch, N, g);
    int hi = lower_bound_i(batch, N, g + 1);
    float acc = 0.f;
#pragma unroll 8
    for (int c = 0; c < HID2; ++c)
        acc = fmaf(pool[g * HID2 + c], Wfc[c * OUT_DIM + o], acc);
    float inv = 1.0f / fmaxf((float)(hi - lo), 1.0f);
    out[g * OUT_DIM + o] = acc * inv + bfc[o];
}

extern "C" void kernel_launch(void* const* d_in, const int* in_sizes, int n_in,
                              void* d_out, int out_size, void* d_ws, size_t ws_size,
                              hipStream_t stream) {
    const float* x   = (const float*)d_in[0];
    const int* src   = (const int*)d_in[1];
    const int* dst   = (const int*)d_in[2];
    const int* batch = (const int*)d_in[3];
    const float* W1  = (const float*)d_in[4];
    const float* b1  = (const float*)d_in[5];
    const float* W2  = (const float*)d_in[6];
    const float* b2  = (const float*)d_in[7];
    const float* Wfc = (const float*)d_in[8];
    const float* bfc = (const float*)d_in[9];
    float* out = (float*)d_out;

    const int N = in_sizes[0] / IN_DIM;  // 50000
    const int E = in_sizes[1];           // 640000
    const int NB = (N + 255) / 256;      // scan blocks (196)
    const int GA = (N + 15) / 16;        // agg blocks (3125; 16 nodes each)
    const int GM = (N + 95) / 96;        // fused-MLP blocks (521; 96 rows each)

    // ---- workspace layout (~30 MB; region aliasing) ----
    char* ws = (char*)d_ws;
    size_t off = 0;
    auto alloc = [&](size_t bytes) {
        char* p = ws + off;
        off = (off + bytes + 255) & ~(size_t)255;
        return p;
    };
    float*  dinv   = (float*) alloc((size_t)N * 4);
    int*    count  = (int*)   alloc((size_t)N * 4);
    int*    rowptr = (int*)   alloc((size_t)(N + 1) * 4);
    int*    bsums  = (int*)   alloc(256 * 4);
    ushort* rank   = (ushort*)alloc((size_t)E * 2);
    ushort* csr    = (ushort*)alloc((size_t)E * 2);
    short*  W1th   = (short*) alloc((size_t)IN_DIM * HID * 2);
    short*  W1tl   = (short*) alloc((size_t)IN_DIM * HID * 2);
    short*  W2th   = (short*) alloc((size_t)HID * HID2 * 2);
    short*  W2tl   = (short*) alloc((size_t)HID * HID2 * 2);
    // region Z (12.8 MB): xb -> later h2b (bf16)
    ushort* xb     = (ushort*)alloc((size_t)N * IN_DIM * 2);
    // region X (12.8 MB): axb (bf16, agg1 out)
    short*  axb    = (short*) alloc((size_t)N * IN_DIM * 2);
    float*  pool   = (float*) alloc((size_t)NGRAPH * HID2 * 4);
    ushort* h2b = xb;              // xb dead after agg1

    // ---- weight prep (fragment order) + count zero + pool zero ----
    wprep_all_kernel<<<(max(IN_DIM * HID, N) + 255) / 256, 256, 0, stream>>>(
        W1, W1th, W1tl, W2, W2th, W2tl, count, pool, N);

    // ---- CSR build (once; serves both layers) ----
    hist_kernel<<<(E + 255) / 256, 256, 0, stream>>>(dst, count, rank, E);
    scan1_kernel<<<NB, 256, 0, stream>>>(count, bsums, N);
    scan3_kernel<<<NB, 256, 0, stream>>>(count, bsums, rowptr, dinv, N, E, NB);
    scatter_scale_kernel<<<(N * 64 + 255) / 256, 256, 0, stream>>>(
        src, dst, rank, rowptr, csr, x, dinv, xb, E, N * 64);

    // ---- layer 1 agg ----
    agg_group_kernel<false><<<GA, 256, 0, stream>>>(
        xb, dinv, rowptr, csr, nullptr, axb, nullptr, nullptr, N);

    // ---- fused MLP (gemm1 + gemm2) ----
    mlp_fused_kernel<<<GM, 256, 0, stream>>>(
        axb, W1th, W1tl, b1, W2th, W2tl, dinv, (short*)h2b, N);

    // ---- layer 2 agg + pool ----
    agg_group_kernel<true><<<GA, 256, 0, stream>>>(
        h2b, dinv, rowptr, csr, b2, nullptr, batch, pool, N);

    // ---- fc ----
    fc_kernel<<<1, NGRAPH * OUT_DIM, 0, stream>>>(pool, batch, Wfc, bfc, out, N);
}

// Round 15
// 224.104 us; speedup vs baseline: 1.0134x; 1.0134x over previous
//
#include <hip/hip_runtime.h>

// GCN forward. All inter-kernel feature traffic in bf16.
//   xb  = bf16(x * dinv_row)                       (fused into scatter)
//   axb = bf16(dd*(Σ_{s} xb[s] + xb[d]))           (agg1, bf16 out)
//   fused MLP: a1 = relu(axb@W1+b1) [LDS only] ; h2b = bf16((a1@W2)*dinv)
//   agg2+pool: pool[g] += relu(dd*(Σ h2b[s] + h2b[d]) + b2)   (fused, no a2b)
//   out = pool/cnt @ Wfc + bfc
// R30: REVERT mlp to R28's 48-row/(256,4) config (225.7us best; R29's 96-row
// halved occupancy for nothing -- weight VOLUME is not the limiter, only the
// PATTERN was). Plus one safe micro-opt: scatter_scale xb path widened to
// float4->ushort4 (16B/thread, grid N*32) -- memory-bound kernel was at 8B/
// thread, half the coalescing sweet spot (G13).
// Ledger: MLP at compute/barrier floor (~27us, R28/R29); aggs at random-
// gather fabric floor (~43us each, R16/R19/R20 triangulation); CSR ~25us.
// R28 (kept): fragment-ordered contiguous weight slabs (the session's big
// win: 48.2 -> ~27us mlp). R20/R17 (kept). 9 dispatches.

constexpr int IN_DIM  = 128;
constexpr int HID     = 256;
constexpr int HID2    = 128;
constexpr int OUT_DIM = 4;
constexpr int NGRAPH  = 64;

typedef __attribute__((ext_vector_type(8))) short bf16x8;
typedef __attribute__((ext_vector_type(4))) float f32x4;

__device__ __forceinline__ short f2bf(float f) {
    union { float f; unsigned u; } v; v.f = f;
    unsigned r = v.u + 0x7fff + ((v.u >> 16) & 1);   // RNE
    return (short)(r >> 16);
}
__device__ __forceinline__ float bf2f(short s) {
    union { unsigned u; float f; } v; v.u = ((unsigned)(unsigned short)s) << 16;
    return v.f;
}

// ------- W prep: FRAGMENT-ORDER planes + count zero + pool zero -------
// W1 plane: 64 slabs of 512 shorts; slab = c4*4 + ks (c4 = col/16, ks = k/32).
//   element i: lane=(i>>3)&63, e=i&7 -> value W1[k][col],
//   col = c4*16 + (lane&15), k = ks*32 + (lane>>4)*8 + e.
// W2 plane: 64 slabs; slab = c4*8 + ks (c4 = col/16, ks = k/32, ks<8).
// A wave's fragment load is then 64 lanes x 16B CONTIGUOUS (1KB streaming).

__global__ void wprep_all_kernel(const float* __restrict__ W1, short* __restrict__ W1fh,
                                 short* __restrict__ W1fl,
                                 const float* __restrict__ W2, short* __restrict__ W2fh,
                                 short* __restrict__ W2fl,
                                 int* __restrict__ count, float* __restrict__ pool, int N) {
    int i = blockIdx.x * blockDim.x + threadIdx.x;
    if (i < IN_DIM * HID) {                    // 32768 = W1 plane
        int slab = i >> 9, lane = (i >> 3) & 63, e = i & 7;
        int c4 = slab >> 2, ks = slab & 3;
        int col = c4 * 16 + (lane & 15);
        int k   = ks * 32 + (lane >> 4) * 8 + e;
        float w = W1[k * HID + col];
        short h = f2bf(w);
        W1fh[i] = h;
        W1fl[i] = f2bf(w - bf2f(h));
    }
    if (i < HID * HID2) {                      // 32768 = W2 plane
        int slab = i >> 9, lane = (i >> 3) & 63, e = i & 7;
        int c4 = slab >> 3, ks = slab & 7;
        int col = c4 * 16 + (lane & 15);
        int k   = ks * 32 + (lane >> 4) * 8 + e;
        float w = W2[k * HID2 + col];
        short h = f2bf(w);
        W2fh[i] = h;
        W2fl[i] = f2bf(w - bf2f(h));
    }
    if (i < N) count[i] = 0;
    if (i < NGRAPH * HID2) pool[i] = 0.f;
}

// ---------------- CSR build ----------------

__global__ void hist_kernel(const int* __restrict__ dst, int* __restrict__ count,
                            ushort* __restrict__ rank, int E) {
    int i = blockIdx.x * blockDim.x + threadIdx.x;
    if (i < E) rank[i] = (ushort)atomicAdd(&count[dst[i]], 1);
}

__global__ void scan1_kernel(const int* __restrict__ count, int* __restrict__ bsums, int N) {
    __shared__ int s[256];
    int t = threadIdx.x, i = blockIdx.x * 256 + t;
    int v = (i < N) ? count[i] : 0;
    s[t] = v; __syncthreads();
    for (int o = 1; o < 256; o <<= 1) {
        int x = (t >= o) ? s[t - o] : 0;
        __syncthreads(); s[t] += x; __syncthreads();
    }
    if (t == 255) bsums[blockIdx.x] = s[255];
}

// scan3: inline-scan the (<=256) raw block sums, then per-element scan of count.
__global__ void scan3_kernel(const int* __restrict__ count, const int* __restrict__ bsums,
                             int* __restrict__ rowptr, float* __restrict__ dinv,
                             int N, int E, int nb) {
    __shared__ int sb[256];
    __shared__ int s[256];
    int t = threadIdx.x, i = blockIdx.x * 256 + t;
    int bv = (t < nb) ? bsums[t] : 0;
    sb[t] = bv; __syncthreads();
    for (int o = 1; o < 256; o <<= 1) {
        int x = (t >= o) ? sb[t - o] : 0;
        __syncthreads(); sb[t] += x; __syncthreads();
    }
    int myex = (blockIdx.x == 0) ? 0 : sb[blockIdx.x - 1];
    int v = (i < N) ? count[i] : 0;
    s[t] = v; __syncthreads();
    for (int o = 1; o < 256; o <<= 1) {
        int x = (t >= o) ? s[t - o] : 0;
        __syncthreads(); s[t] += x; __syncthreads();
    }
    if (i < N) {
        rowptr[i] = myex + s[t] - v;
        dinv[i] = rsqrtf((float)v + 1.0f);
        if (i == 0) rowptr[N] = E;
    }
}

// scatter (no atomics: p = rowptr[dst]+rank) + xb = bf16(x * dinv_row)
// xb path widened to float4 -> ushort4 (16B/thread; total4 = N*32 threads).
__global__ void scatter_scale_kernel(const int* __restrict__ src, const int* __restrict__ dst,
                                     const ushort* __restrict__ rank,
                                     const int* __restrict__ rowptr, ushort* __restrict__ csr,
                                     const float* __restrict__ x, const float* __restrict__ dinv,
                                     ushort* __restrict__ xb, int E, int total4) {
    int i = blockIdx.x * blockDim.x + threadIdx.x;
    if (i < E) {
        int p = rowptr[dst[i]] + (int)rank[i];
        csr[p] = (ushort)src[i];
    }
    if (i < total4) {
        float d = dinv[i >> 5];                    // 32 float4 per 128-dim row
        float4 v = ((const float4*)x)[i];
        ushort4 o;
        o.x = (ushort)f2bf(v.x * d);
        o.y = (ushort)f2bf(v.y * d);
        o.z = (ushort)f2bf(v.z * d);
        o.w = (ushort)f2bf(v.w * d);
        ((ushort4*)xb)[i] = o;
    }
}

// ---------------- fused MLP: h2b = bf16((relu(axb@W1+b1)@W2)*dinv) ----------------
// One block per 48-row M-tile (grid 1042), 256 thr = 4 waves. R28 config:
// in-loop weight loads, launch_bounds(256,4), LDS 37KB, fragment-ordered
// weights -> one wave-load = contiguous 1KB slab.
//   W1 slab = ((w*4+n)*4+ks)*512;  W2 slab = ((w*2+n)*8+ks)*512; + lane*8.
// A0: axb tile in frag layout (12 KB). A1 (24 KB): a1 in frag layout, identity:
//   element (r,c) -> slab m*8+(c>>5), lane d=(r&15)+16*((c>>3)&3), elem c&7
// OUT (48x132) overlays A1 after phase2. 4 barriers. Bit-identical numerics.

__launch_bounds__(256, 4)
__global__ void mlp_fused_kernel(const short* __restrict__ A,
                                 const short* __restrict__ W1h, const short* __restrict__ W1l,
                                 const float* __restrict__ b1,
                                 const short* __restrict__ W2h, const short* __restrict__ W2l,
                                 const float* __restrict__ dinv,
                                 short* __restrict__ Cb, int M) {
    __shared__ __align__(16) short L[12288 + 6144];   // A1 (24 slabs) | A0 (12 slabs)
    short* A1 = L;
    short* A0 = L + 12288;
    __shared__ float dinv_s[48];

    const int tid  = threadIdx.x;
    const int w    = tid >> 6;
    const int lane = tid & 63;
    const int l15  = lane & 15;
    const int kq8  = (lane >> 4) * 8;
    const int row0 = blockIdx.x * 48;

    // ---- stage A0 (12 slabs; wave w -> slabs 3w..3w+2) ----
    {
        bf16x8 stg[3];
#pragma unroll
        for (int j = 0; j < 3; ++j) {
            int s = w * 3 + j;
            int m = s >> 2, ks = s & 3;
            int rr = row0 + m * 16 + l15; if (rr >= M) rr = M - 1;
            stg[j] = *(const bf16x8*)(A + (size_t)rr * IN_DIM + ks * 32 + kq8);
        }
#pragma unroll
        for (int j = 0; j < 3; ++j)
            *(bf16x8*)&A0[(w * 3 + j) * 512 + lane * 8] = stg[j];
    }
    if (tid < 48) { int r = row0 + tid; dinv_s[tid] = dinv[r < M ? r : M - 1]; }
    __syncthreads();

    // ---- phase 1: a1 = axb @ W1^T (split B), K=128; contiguous slab loads ----
    f32x4 acc1[3][4];
#pragma unroll
    for (int m = 0; m < 3; ++m)
#pragma unroll
        for (int n = 0; n < 4; ++n) acc1[m][n] = f32x4{0.f, 0.f, 0.f, 0.f};

#pragma unroll
    for (int ks = 0; ks < 4; ++ks) {
        bf16x8 af[3], bh[4], bl[4];
#pragma unroll
        for (int m = 0; m < 3; ++m) af[m] = *(const bf16x8*)&A0[(m * 4 + ks) * 512 + lane * 8];
#pragma unroll
        for (int n = 0; n < 4; ++n) {
            int slab = ((w * 4 + n) * 4 + ks) * 512;
            bh[n] = *(const bf16x8*)(W1h + slab + lane * 8);
            bl[n] = *(const bf16x8*)(W1l + slab + lane * 8);
        }
#pragma unroll
        for (int m = 0; m < 3; ++m)
#pragma unroll
            for (int n = 0; n < 4; ++n) {
                acc1[m][n] = __builtin_amdgcn_mfma_f32_16x16x32_bf16(af[m], bh[n], acc1[m][n], 0, 0, 0);
                acc1[m][n] = __builtin_amdgcn_mfma_f32_16x16x32_bf16(af[m], bl[n], acc1[m][n], 0, 0, 0);
            }
    }

    // ---- bias + relu + bf16, transpose-write into A1 (identity mapping) ----
#pragma unroll
    for (int n = 0; n < 4; ++n) {
        int c  = w * 64 + n * 16 + l15;
        float bv = b1[c];
        int kst = c >> 5;
        int q  = (c >> 3) & 3;
        int e  = c & 7;
#pragma unroll
        for (int m = 0; m < 3; ++m)
#pragma unroll
            for (int r4 = 0; r4 < 4; ++r4) {
                int rl = (lane >> 4) * 4 + r4;                 // r & 15
                int d  = rl + 16 * q;                          // dest lane 0..63
                float v = fmaxf(acc1[m][n][r4] + bv, 0.f);
                A1[(m * 8 + kst) * 512 + d * 8 + e] = f2bf(v);
            }
    }
    __syncthreads();

    // ---- phase 2: h2 = a1 @ W2^T (split B), K=256; contiguous slab loads ----
    f32x4 acc2[3][2];
#pragma unroll
    for (int m = 0; m < 3; ++m)
#pragma unroll
        for (int n = 0; n < 2; ++n) acc2[m][n] = f32x4{0.f, 0.f, 0.f, 0.f};

#pragma unroll
    for (int ks = 0; ks < 8; ++ks) {
        bf16x8 af[3], bh[2], bl[2];
#pragma unroll
        for (int m = 0; m < 3; ++m) af[m] = *(const bf16x8*)&A1[(m * 8 + ks) * 512 + lane * 8];
#pragma unroll
        for (int n = 0; n < 2; ++n) {
            int slab = ((w * 2 + n) * 8 + ks) * 512;
            bh[n] = *(const bf16x8*)(W2h + slab + lane * 8);
            bl[n] = *(const bf16x8*)(W2l + slab + lane * 8);
        }
#pragma unroll
        for (int m = 0; m < 3; ++m)
#pragma unroll
            for (int n = 0; n < 2; ++n) {
                acc2[m][n] = __builtin_amdgcn_mfma_f32_16x16x32_bf16(af[m], bh[n], acc2[m][n], 0, 0, 0);
                acc2[m][n] = __builtin_amdgcn_mfma_f32_16x16x32_bf16(af[m], bl[n], acc2[m][n], 0, 0, 0);
            }
    }
    __syncthreads();          // A1 reads done before OUT overlays it

    // ---- epilogue: dinv scale -> OUT tile (overlays A1) -> coalesced store ----
    short* T = A1;                                    // 48 x 132 shorts
#pragma unroll
    for (int n = 0; n < 2; ++n) {
        int c = w * 32 + n * 16 + l15;
#pragma unroll
        for (int m = 0; m < 3; ++m)
#pragma unroll
            for (int r4 = 0; r4 < 4; ++r4) {
                int r = m * 16 + (lane >> 4) * 4 + r4;
                T[r * 132 + c] = f2bf(acc2[m][n][r4] * dinv_s[r]);
            }
    }
    __syncthreads();
#pragma unroll
    for (int it = 0; it < 3; ++it) {
        int chunk = it * 256 + tid;                   // 768 chunks of 8 shorts
        int lr = chunk >> 4;
        int lc = (chunk & 15) * 8;
        int gr = row0 + lr;
        if (gr < M)
            *(bf16x8*)(Cb + (size_t)gr * HID2 + lc) = *(const bf16x8*)&T[lr * 132 + lc];
    }
}

// ---------------- group-per-node bf16 gather aggregation (D=128) ----------------
// One 16-lane group per dst node: 4 nodes/wave, 16 nodes/block (256 thr).
// 16 clamped 16B gathers issued per 16-edge chunk before accumulation
// -> 32-64 independent loads in flight per wave. 256B contiguous writes.
// POOL: bias+relu then 16-node LDS block-reduce by graph run -> atomicAdd.

template <bool POOL>
__launch_bounds__(256)
__global__ void agg_group_kernel(const ushort* __restrict__ hb, const float* __restrict__ dinv,
                                 const int* __restrict__ rowptr, const ushort* __restrict__ csr,
                                 const float* __restrict__ bias,
                                 short* __restrict__ oh,
                                 const int* __restrict__ batch, float* __restrict__ pool,
                                 int N) {
    __shared__ float pacc[16][128];
    __shared__ int   sgid[16];

    const int tid  = threadIdx.x;
    const int li   = tid & 15;
    const int nib  = tid >> 4;
    const int node = blockIdx.x * 16 + nib;
    const bool valid = node < N;
    if (!POOL && !valid) return;
    const int cw = valid ? node : N - 1;

    const int lo = rowptr[cw], hi = rowptr[cw + 1];
    const float dd = dinv[cw];

    float a[8];
    {
        bf16x8 sv = *(const bf16x8*)(hb + ((size_t)cw << 7) + (li << 3));
#pragma unroll
        for (int d = 0; d < 8; ++d) a[d] = bf2f(sv[d]);
    }

    const ushort* hsl = hb + (li << 3);

    for (int base = lo; base < hi; base += 16) {
        int cnt = min(16, hi - base);
        int sidx = (int)csr[base + (li < cnt ? li : cnt - 1)];
        bf16x8 p[8], q[8];
#pragma unroll
        for (int u = 0; u < 8; ++u) {
            int s = __shfl(sidx, u < cnt ? u : cnt - 1, 16);
            p[u] = *(const bf16x8*)(hsl + ((size_t)s << 7));
        }
#pragma unroll
        for (int u = 0; u < 8; ++u) {
            int e = 8 + u;
            int s = __shfl(sidx, e < cnt ? e : cnt - 1, 16);
            q[u] = *(const bf16x8*)(hsl + ((size_t)s << 7));
        }
#pragma unroll
        for (int u = 0; u < 8; ++u) {
            bool v = u < cnt;
#pragma unroll
            for (int d = 0; d < 8; ++d) a[d] += v ? bf2f(p[u][d]) : 0.f;
        }
#pragma unroll
        for (int u = 0; u < 8; ++u) {
            bool v = 8 + u < cnt;
#pragma unroll
            for (int d = 0; d < 8; ++d) a[d] += v ? bf2f(q[u][d]) : 0.f;
        }
    }

#pragma unroll
    for (int d = 0; d < 8; ++d) a[d] *= dd;

    if (!POOL) {
        if (valid) {
            bf16x8 o;
#pragma unroll
            for (int d = 0; d < 8; ++d) o[d] = f2bf(a[d]);
            *(bf16x8*)&oh[(size_t)node * 128 + li * 8] = o;
        }
        return;
    }

    {
        float4 b0 = ((const float4*)bias)[li * 2];
        float4 b1 = ((const float4*)bias)[li * 2 + 1];
        a[0] = fmaxf(a[0] + b0.x, 0.f); a[1] = fmaxf(a[1] + b0.y, 0.f);
        a[2] = fmaxf(a[2] + b0.z, 0.f); a[3] = fmaxf(a[3] + b0.w, 0.f);
        a[4] = fmaxf(a[4] + b1.x, 0.f); a[5] = fmaxf(a[5] + b1.y, 0.f);
        a[6] = fmaxf(a[6] + b1.z, 0.f); a[7] = fmaxf(a[7] + b1.w, 0.f);
    }
    if (li == 0) sgid[nib] = valid ? batch[node] : -1;
#pragma unroll
    for (int d = 0; d < 8; ++d) pacc[nib][li * 8 + d] = a[d];
    __syncthreads();
    if (tid < 128) {
        int c = tid;
        int cur = sgid[0];
        float run = 0.f;
#pragma unroll 1
        for (int w = 0; w < 16; ++w) {
            int gi = sgid[w];
            if (gi < 0) break;
            if (gi != cur) { atomicAdd(&pool[cur * HID2 + c], run); run = 0.f; cur = gi; }
            run += pacc[w][c];
        }
        atomicAdd(&pool[cur * HID2 + c], run);
    }
}

// ---------------- fc ----------------

__device__ __forceinline__ int lower_bound_i(const int* __restrict__ a, int n, int key) {
    int lo = 0, hi = n;
    while (lo < hi) {
        int mid = (lo + hi) >> 1;
        if (a[mid] < key) lo = mid + 1; else hi = mid;
    }
    return lo;
}

__global__ void fc_kernel(const float* __restrict__ pool, const int* __restrict__ batch,
                          const float* __restrict__ Wfc, const float* __restrict__ bfc,
                          float* __restrict__ out, int N) {
    int t = threadIdx.x;  // 256 = 64 graphs * 4 outputs
    int g = t >> 2, o = t & 3;
    int lo = lower_bound_i(batch, N, g);
    int hi = lower_bound_i(batch, N, g + 1);
    float acc = 0.f;
#pragma unroll 8
    for (int c = 0; c < HID2; ++c)
        acc = fmaf(pool[g * HID2 + c], Wfc[c * OUT_DIM + o], acc);
    float inv = 1.0f / fmaxf((float)(hi - lo), 1.0f);
    out[g * OUT_DIM + o] = acc * inv + bfc[o];
}

extern "C" void kernel_launch(void* const* d_in, const int* in_sizes, int n_in,
                              void* d_out, int out_size, void* d_ws, size_t ws_size,
                              hipStream_t stream) {
    const float* x   = (const float*)d_in[0];
    const int* src   = (const int*)d_in[1];
    const int* dst   = (const int*)d_in[2];
    const int* batch = (const int*)d_in[3];
    const float* W1  = (const float*)d_in[4];
    const float* b1  = (const float*)d_in[5];
    const float* W2  = (const float*)d_in[6];
    const float* b2  = (const float*)d_in[7];
    const float* Wfc = (const float*)d_in[8];
    const float* bfc = (const float*)d_in[9];
    float* out = (float*)d_out;

    const int N = in_sizes[0] / IN_DIM;  // 50000
    const int E = in_sizes[1];           // 640000
    const int NB = (N + 255) / 256;      // scan blocks (196)
    const int GA = (N + 15) / 16;        // agg blocks (3125; 16 nodes each)
    const int GM = (N + 47) / 48;        // fused-MLP blocks (1042)

    // ---- workspace layout (~30 MB; region aliasing) ----
    char* ws = (char*)d_ws;
    size_t off = 0;
    auto alloc = [&](size_t bytes) {
        char* p = ws + off;
        off = (off + bytes + 255) & ~(size_t)255;
        return p;
    };
    float*  dinv   = (float*) alloc((size_t)N * 4);
    int*    count  = (int*)   alloc((size_t)N * 4);
    int*    rowptr = (int*)   alloc((size_t)(N + 1) * 4);
    int*    bsums  = (int*)   alloc(256 * 4);
    ushort* rank   = (ushort*)alloc((size_t)E * 2);
    ushort* csr    = (ushort*)alloc((size_t)E * 2);
    short*  W1th   = (short*) alloc((size_t)IN_DIM * HID * 2);
    short*  W1tl   = (short*) alloc((size_t)IN_DIM * HID * 2);
    short*  W2th   = (short*) alloc((size_t)HID * HID2 * 2);
    short*  W2tl   = (short*) alloc((size_t)HID * HID2 * 2);
    // region Z (12.8 MB): xb -> later h2b (bf16)
    ushort* xb     = (ushort*)alloc((size_t)N * IN_DIM * 2);
    // region X (12.8 MB): axb (bf16, agg1 out)
    short*  axb    = (short*) alloc((size_t)N * IN_DIM * 2);
    float*  pool   = (float*) alloc((size_t)NGRAPH * HID2 * 4);
    ushort* h2b = xb;              // xb dead after agg1

    // ---- weight prep (fragment order) + count zero + pool zero ----
    wprep_all_kernel<<<(max(IN_DIM * HID, N) + 255) / 256, 256, 0, stream>>>(
        W1, W1th, W1tl, W2, W2th, W2tl, count, pool, N);

    // ---- CSR build (once; serves both layers) ----
    hist_kernel<<<(E + 255) / 256, 256, 0, stream>>>(dst, count, rank, E);
    scan1_kernel<<<NB, 256, 0, stream>>>(count, bsums, N);
    scan3_kernel<<<NB, 256, 0, stream>>>(count, bsums, rowptr, dinv, N, E, NB);
    scatter_scale_kernel<<<(max(E, N * 32) + 255) / 256, 256, 0, stream>>>(
        src, dst, rank, rowptr, csr, x, dinv, xb, E, N * 32);

    // ---- layer 1 agg ----
    agg_group_kernel<false><<<GA, 256, 0, stream>>>(
        xb, dinv, rowptr, csr, nullptr, axb, nullptr, nullptr, N);

    // ---- fused MLP (gemm1 + gemm2) ----
    mlp_fused_kernel<<<GM, 256, 0, stream>>>(
        axb, W1th, W1tl, b1, W2th, W2tl, dinv, (short*)h2b, N);

    // ---- layer 2 agg + pool ----
    agg_group_kernel<true><<<GA, 256, 0, stream>>>(
        h2b, dinv, rowptr, csr, b2, nullptr, batch, pool, N);

    // ---- fc ----
    fc_kernel<<<1, NGRAPH * OUT_DIM, 0, stream>>>(pool, batch, Wfc, bfc, out, N);
}